// Round 3
// baseline (436.721 us; speedup 1.0000x reference)
//
#include <hip/hip_runtime.h>
#include <cstdint>
#include <cstddef>

// ---------------------------------------------------------------------------
// GCN: h = elu(D^-1/2 (A+I) D^-1/2 (h W) + b) x3, mean-pool, MLP head.
// R17: full-wave-per-node gather. R16 post-mortem: fused gather_gemm 57us vs
// 43us unfused -> the __syncthreads makes block time = max over 16 nodes of
// deg (~1.6x mean, Poisson tail). Fix: 1 wave per node, edge list split
// between lane halves (each lane keeps its 4-feature slice), combined with
// one shfl_xor(32) of the packed-f16 accumulators. Doubles outstanding
// row-loads per node AND halves the serial depth / barrier tail.
// Block = 8 nodes (512 thr); MFMA A-tile rows 8-15 zeroed, write masked.
// ---------------------------------------------------------------------------

#define SUBCAP 512   // per-(bucket,XCD) capacity: mean 256, +16 sigma
#define CSRCAP 4608  // per-bucket csr region: 4096 max edges + ceil4 padding
#define TILE 4096    // edges per scatter block

typedef __attribute__((ext_vector_type(8))) short short8;   // 8 bf16 = 4 VGPRs
typedef __attribute__((ext_vector_type(4))) float f32x4;
typedef __attribute__((ext_vector_type(2))) _Float16 h16x2; // packed f16 pair

__device__ __forceinline__ float bf2f(uint32_t u) {
  return __uint_as_float(u << 16);
}
__device__ __forceinline__ uint32_t f2bf(float f) {  // round-to-nearest-even
  uint32_t x = __float_as_uint(f);
  return (x + 0x7FFFu + ((x >> 16) & 1u)) >> 16;
}

union H16 { _Float16 h; uint16_t u; };
union H2U { h16x2 h; uint32_t u; };

// f32 -> e5m2 byte (RNE via f16 then RNE-truncate mantissa to 2 bits)
__device__ __forceinline__ uint32_t f2e5m2(float f) {
  f = fminf(fmaxf(f, -30000.f), 30000.f);
  H16 cv;
  cv.h = (_Float16)f;
  uint32_t h = cv.u;
  uint32_t r = h + 0x7Fu + ((h >> 8) & 1u);
  return (r >> 8) & 0xFFu;
}

// e5m2 byte -> f32 (exact: e5m2 is truncated f16)
__device__ __forceinline__ float e5m2f(uint32_t b) {
  H16 cv;
  cv.u = (uint16_t)(b << 8);
  return (float)cv.h;
}

// ---------------- CSR build ----------------

// Block-aggregated, XCD-partitioned scatter. 4096 edges/block. (R10)
__global__ __launch_bounds__(256) void bucket_scatter(const int* __restrict__ src,
                                                      const int* __restrict__ dst,
                                                      int* __restrict__ bcur,
                                                      uint32_t* __restrict__ ebuf,
                                                      int nE, int nbuk) {
  uint32_t xcc;
  asm("s_getreg_b32 %0, hwreg(HW_REG_XCC_ID)" : "=s"(xcc));  // 0..7, wave-uniform
  __shared__ int lhist[1024];
  __shared__ int gbase[1024];
  int t = threadIdx.x;
  for (int i = t; i < nbuk; i += 256) lhist[i] = 0;
  __syncthreads();

  int e0 = blockIdx.x * TILE;
  int myd[16], mys[16], myrank[16];
#pragma unroll
  for (int j = 0; j < 16; ++j) {
    int e = e0 + t + j * 256;  // coalesced
    if (e < nE) {
      int d = dst[e];
      myd[j] = d;
      mys[j] = src[e];
      myrank[j] = atomicAdd(&lhist[d >> 7], 1);  // returns old -> local rank
    } else {
      myd[j] = -1;
    }
  }
  __syncthreads();
  for (int i = t; i < nbuk; i += 256) {
    int c = lhist[i];
    gbase[i] = c ? atomicAdd(&bcur[((i << 3) | (int)xcc) * 16], c) : 0;
  }
  __syncthreads();
#pragma unroll
  for (int j = 0; j < 16; ++j) {
    if (myd[j] >= 0) {
      int b = myd[j] >> 7;
      int pos = gbase[b] + myrank[j];
      if (pos < SUBCAP) {
        int sub = (b << 3) | (int)xcc;
        ebuf[(size_t)sub * SUBCAP + pos] =
            ((uint32_t)(myd[j] & 127) << 20) | (uint32_t)mys[j];
      }
    }
  }
}

// Fused hist + prefix + fill (R12) + side jobs: W cvt, pool zero (R14).
__global__ __launch_bounds__(256) void bucket_build(const uint32_t* __restrict__ ebuf,
                                                    const int* __restrict__ bcur,
                                                    int* __restrict__ deg,
                                                    float* __restrict__ dinv,
                                                    int* __restrict__ offs,
                                                    int* __restrict__ csr,
                                                    const float* __restrict__ W1,
                                                    const float* __restrict__ W2,
                                                    const float* __restrict__ W3,
                                                    uint16_t* __restrict__ WT,
                                                    float* __restrict__ pool,
                                                    int n, int nbuk) {
  int b = blockIdx.x;
  int base = b << 7;
  __shared__ int hist[128];
  __shared__ int pre[128];
  __shared__ int lcur[128];
  int t = threadIdx.x;

  // Side job 1: W1,W2,W3 fp32 [k][nn] -> WT bf16 [w][nn][k]  (grid-stride)
  for (int id = b * 256 + t; id < 3 * 16384; id += nbuk * 256) {
    int w = id >> 14;
    int rem = id & 16383;
    int k = rem >> 7, nn = rem & 127;
    const float* W = (w == 0) ? W1 : ((w == 1) ? W2 : W3);
    WT[w * 16384 + nn * 128 + k] = (uint16_t)f2bf(W[k * 128 + nn]);
  }
  // Side job 2: zero pool
  for (int id = b * 256 + t; id < 64 * 128; id += nbuk * 256) pool[id] = 0.f;

  if (t < 128) hist[t] = 0;
  __syncthreads();
  int cnts[8];
#pragma unroll
  for (int x = 0; x < 8; ++x) {
    int sub = (b << 3) | x;
    int cnt = min(bcur[sub * 16], SUBCAP);
    cnts[x] = cnt;
    const uint32_t* eb = ebuf + (size_t)sub * SUBCAP;
    for (int e = t; e < cnt; e += 256) atomicAdd(&hist[eb[e] >> 20], 1);
  }
  __syncthreads();
  if (t < 128) pre[t] = (hist[t] + 3) & ~3;  // ceil4 region sizes
  __syncthreads();
  for (int d = 1; d < 128; d <<= 1) {  // inclusive scan
    int v = (t >= d && t < 128) ? pre[t - d] : 0;
    __syncthreads();
    if (t < 128) pre[t] += v;
    __syncthreads();
  }
  if (t < 128) {
    int dg = hist[t];
    int start = b * CSRCAP + pre[t] - ((dg + 3) & ~3);  // 4-aligned
    lcur[t] = start;
    if (base + t < n) {
      deg[base + t] = dg;
      dinv[base + t] = rsqrtf((float)(dg + 1));  // +1 self-loop
      offs[base + t] = start;
    }
  }
  __syncthreads();
#pragma unroll
  for (int x = 0; x < 8; ++x) {
    int sub = (b << 3) | x;
    int cnt = cnts[x];
    const uint32_t* eb = ebuf + (size_t)sub * SUBCAP;
    for (int e = t; e < cnt; e += 256) {
      uint32_t ed = eb[e];
      int pos = atomicAdd(&lcur[ed >> 20], 1);
      csr[pos] = (int)((ed & 0xFFFFFu) << 7);  // byte offset into fp8 table
    }
  }
}

// ---------------- MFMA GEMM (layer 1 only): fp32 in, fp8(e5m2) table out ----

template <bool F32IN>
__global__ __launch_bounds__(256) void gemm_mfma(const uint16_t* __restrict__ Xb,
                                                 const float* __restrict__ X32,
                                                 const uint16_t* __restrict__ WTb,
                                                 const float* __restrict__ dinv,
                                                 uint8_t* __restrict__ tab, int n) {
  __shared__ uint16_t sW[128 * 136];
  int t = threadIdx.x;
#pragma unroll
  for (int i = 0; i < 8; ++i) {
    int j = t + i * 256;
    int r = j >> 4, c = j & 15;
    float4 v = ((const float4*)WTb)[j];
    *(float4*)(sW + r * 136 + c * 8) = v;
  }
  __syncthreads();

  int wave = t >> 6, lane = t & 63;
  int quad = lane >> 4, l15 = lane & 15;
  int m = blockIdx.x * 64 + wave * 16 + l15;
  int mm = min(m, n - 1);

  short8 a[4];
#pragma unroll
  for (int kc = 0; kc < 4; ++kc) {
    if constexpr (F32IN) {
      const float* p = X32 + (size_t)mm * 128 + kc * 32 + quad * 8;
      float4 lo = *(const float4*)p;
      float4 hi = *(const float4*)(p + 4);
      a[kc] = (short8){(short)f2bf(lo.x), (short)f2bf(lo.y),
                       (short)f2bf(lo.z), (short)f2bf(lo.w),
                       (short)f2bf(hi.x), (short)f2bf(hi.y),
                       (short)f2bf(hi.z), (short)f2bf(hi.w)};
    } else {
      a[kc] = *(const short8*)(Xb + (size_t)mm * 128 + kc * 32 + quad * 8);
    }
  }

  f32x4 acc[8];
#pragma unroll
  for (int nn = 0; nn < 8; ++nn) acc[nn] = (f32x4){0.f, 0.f, 0.f, 0.f};

#pragma unroll
  for (int nn = 0; nn < 8; ++nn) {
    int nrow = nn * 16 + l15;
#pragma unroll
    for (int kc = 0; kc < 4; ++kc) {
      short8 b = *(const short8*)(sW + nrow * 136 + kc * 32 + quad * 8);
      acc[nn] = __builtin_amdgcn_mfma_f32_16x16x32_bf16(a[kc], b, acc[nn], 0, 0, 0);
    }
  }

  int mrow = blockIdx.x * 64 + wave * 16 + quad * 4;
#pragma unroll
  for (int r = 0; r < 4; ++r) {
    int row = mrow + r;
    if (row < n) {
      float dn = dinv[row];
#pragma unroll
      for (int nn = 0; nn < 8; ++nn) {
        tab[(size_t)row * 128 + nn * 16 + l15] = (uint8_t)f2e5m2(acc[nn][r] * dn);
      }
    }
  }
}

// ---------------- fused gather (+ next-layer GEMM | + pool) ----------------

__device__ __forceinline__ void acc_pk(uint32_t u, h16x2& a01, h16x2& a23) {
  H2U p01, p23;
  p01.u = __builtin_amdgcn_perm(u, 0u, 0x05010400u);  // (b0<<8)|(b1<<24)
  p23.u = __builtin_amdgcn_perm(u, 0u, 0x07010600u);  // (b2<<8)|(b3<<24)
  a01 += p01.h;
  a23 += p23.h;
}

// 512 threads = 8 waves = 8 nodes/block. One FULL wave per node: lanes 0-31
// process [e0,emid), lanes 32-63 process [emid,e1), each lane owns the same
// 4-feature slice in both halves; combine with shfl_xor(32) (f16 sums of
// e5m2 are exact, so the split is bit-stable). Phase 2 (!POOL): 8 waves x
// 4 MFMA on the 16-row A-tile (rows 8-15 zero) -> tabN = fp8(dinv*(h W)).
// Phase 2 (POOL): threads 0..127 mean-pool the 8 rows straight from LDS.
template <bool POOL>
__global__ __launch_bounds__(512) void gather_gemm(const uint8_t* __restrict__ tab,
                                                   const int* __restrict__ csr,
                                                   const int* __restrict__ offs,
                                                   const int* __restrict__ deg,
                                                   const float* __restrict__ dinv,
                                                   const float* __restrict__ b,
                                                   const uint16_t* __restrict__ WTb,
                                                   uint8_t* __restrict__ tabN,
                                                   const int* __restrict__ batch,
                                                   float* __restrict__ pool,
                                                   int n) {
  __shared__ uint16_t sW[POOL ? 8 : 128 * 136];  // B operand (W^T)
  __shared__ uint16_t sA[16 * 136];              // h rows (8 used), bf16
  __shared__ int sb[8];                          // batch ids (POOL)
  int t = threadIdx.x;
  int blk = (int)blockIdx.x;

  if constexpr (!POOL) {
#pragma unroll
    for (int i = 0; i < 4; ++i) {
      int j = t + i * 512;  // 2048 float4 = 128x128 bf16
      int r = j >> 4, c = j & 15;
      float4 v = ((const float4*)WTb)[j];
      *(float4*)(sW + r * 136 + c * 8) = v;
    }
    // zero A-tile rows 8..15 (read by MFMA, never written by gather)
    for (int i = t; i < 8 * 136; i += 512) sA[8 * 136 + i] = 0;
  } else {
    if (t < 8) sb[t] = batch[min(blk * 8 + t, n - 1)];
  }

  // ---- phase 1: gather, full wave per node, split edge list ----
  int wv = t >> 6;       // 0..7 = node slot
  int lane = t & 63;
  int g = lane >> 5;     // half-wave id: which edge slice
  int l = lane & 31;
  int node = min(blk * 8 + wv, n - 1);
  int c = l * 4;  // feature/byte offset within row
  const uint8_t* tabc = tab + c;

  int dg = deg[node];
  int e0 = offs[node];  // 4-aligned by construction
  int e1 = e0 + dg;
  int half4 = (((dg + 1) >> 1) + 3) & ~3;  // 4-aligned split point
  int emid = e0 + half4;
  if (emid > e1) emid = e1;
  int myb = g ? emid : e0;
  int mye = g ? e1 : emid;

  h16x2 a01 = (h16x2){(_Float16)0.f, (_Float16)0.f};
  h16x2 a23 = (h16x2){(_Float16)0.f, (_Float16)0.f};

  int e = myb;
  for (; e + 7 < mye; e += 8) {
    int4 ca = *(const int4*)(csr + e);
    int4 cb = *(const int4*)(csr + e + 4);
    uint32_t u[8];
    u[0] = *(const uint32_t*)(tabc + ca.x);
    u[1] = *(const uint32_t*)(tabc + ca.y);
    u[2] = *(const uint32_t*)(tabc + ca.z);
    u[3] = *(const uint32_t*)(tabc + ca.w);
    u[4] = *(const uint32_t*)(tabc + cb.x);
    u[5] = *(const uint32_t*)(tabc + cb.y);
    u[6] = *(const uint32_t*)(tabc + cb.z);
    u[7] = *(const uint32_t*)(tabc + cb.w);
#pragma unroll
    for (int j = 0; j < 8; ++j) acc_pk(u[j], a01, a23);
  }
  if (e + 3 < mye) {
    int4 ca = *(const int4*)(csr + e);
    uint32_t u[4];
    u[0] = *(const uint32_t*)(tabc + ca.x);
    u[1] = *(const uint32_t*)(tabc + ca.y);
    u[2] = *(const uint32_t*)(tabc + ca.z);
    u[3] = *(const uint32_t*)(tabc + ca.w);
#pragma unroll
    for (int j = 0; j < 4; ++j) acc_pk(u[j], a01, a23);
    e += 4;
  }
  for (; e < mye; ++e) acc_pk(*(const uint32_t*)(tabc + csr[e]), a01, a23);

  // combine the two edge-slice partials (lane l <-> lane l+32)
  H2U x01, x23, y01, y23;
  x01.h = a01;
  x23.h = a23;
  y01.u = (uint32_t)__shfl_xor((int)x01.u, 32, 64);
  y23.u = (uint32_t)__shfl_xor((int)x23.u, 32, 64);
  a01 = x01.h + y01.h;
  a23 = x23.h + y23.h;

  float a0 = (float)a01.x, a1 = (float)a01.y;
  float a2 = (float)a23.x, a3 = (float)a23.y;

  float dn = dinv[node];
  uint32_t uh = *(const uint32_t*)(tabc + node * 128);  // self-loop
  float4 bb = *(const float4*)(b + c);
  float o0 = (a0 + e5m2f(uh & 0xFFu)) * dn + bb.x;
  float o1 = (a1 + e5m2f((uh >> 8) & 0xFFu)) * dn + bb.y;
  float o2 = (a2 + e5m2f((uh >> 16) & 0xFFu)) * dn + bb.z;
  float o3 = (a3 + e5m2f(uh >> 24)) * dn + bb.w;
  o0 = o0 > 0.f ? o0 : expm1f(o0);
  o1 = o1 > 0.f ? o1 : expm1f(o1);
  o2 = o2 > 0.f ? o2 : expm1f(o2);
  o3 = o3 > 0.f ? o3 : expm1f(o3);
  if (g == 0) {
    uint2 po;
    po.x = f2bf(o0) | (f2bf(o1) << 16);
    po.y = f2bf(o2) | (f2bf(o3) << 16);
    *(uint2*)(sA + wv * 136 + c) = po;  // h row -> LDS (bf16)
  }
  __syncthreads();

  if constexpr (POOL) {
    // ---- phase 2: sorted-batch mean-pool straight from LDS ----
    if (t < 128) {
      int base = blk * 8;
      int iend = min(8, n - base);
      float acc = 0.f;
      int cur = sb[0];
      for (int i = 0; i < iend; ++i) {
        int gg = sb[i];
        if (gg != cur) {
          atomicAdd(&pool[cur * 128 + t], acc);
          acc = 0.f;
          cur = gg;
        }
        acc += bf2f((uint32_t)sA[i * 136 + t]);
      }
      atomicAdd(&pool[cur * 128 + t], acc);
    }
  } else {
    // ---- phase 2: 8x128 @ 128x128 MFMA (16-row tile, top 8 valid) ----
    int wave = t >> 6;
    int quad = lane >> 4, l15 = lane & 15;
    f32x4 acc = (f32x4){0.f, 0.f, 0.f, 0.f};
#pragma unroll
    for (int kc = 0; kc < 4; ++kc) {
      short8 av = *(const short8*)(sA + l15 * 136 + kc * 32 + quad * 8);
      short8 bv = *(const short8*)(sW + (wave * 16 + l15) * 136 + kc * 32 + quad * 8);
      acc = __builtin_amdgcn_mfma_f32_16x16x32_bf16(av, bv, acc, 0, 0, 0);
    }
    if (quad < 2) {  // tile rows 0..7 only
      int mrow = blk * 8 + quad * 4;
#pragma unroll
      for (int r = 0; r < 4; ++r) {
        int row = mrow + r;
        if (row < n) {
          float dno = dinv[row];
          tabN[(size_t)row * 128 + wave * 16 + l15] = (uint8_t)f2e5m2(acc[r] * dno);
        }
      }
    }
  }
}

// ---------------- head ----------------

// One wave per graph: cnt (binary search), z_j = relu(g.Wc1_j + bc1_j),
// logit = shfl-reduce(z_j * Wc2_j) + bc2. Coalesced Wc1 reads (lane = j).
__global__ __launch_bounds__(64) void classifier_kernel(const float* __restrict__ pool,
                                                        const int* __restrict__ batch,
                                                        const float* __restrict__ Wc1,
                                                        const float* __restrict__ bc1,
                                                        const float* __restrict__ Wc2,
                                                        const float* __restrict__ bc2,
                                                        float* __restrict__ out, int n) {
  int g = blockIdx.x;   // graph id, 0..63
  int j = threadIdx.x;  // hidden unit, 0..63
  __shared__ float sg[128];

  // cnt for this graph (all lanes redundantly; 2 binary searches)
  int lo = 0, hi = n;
  while (lo < hi) {
    int mid = (lo + hi) >> 1;
    if (batch[mid] < g) lo = mid + 1; else hi = mid;
  }
  int a = lo;
  lo = 0; hi = n;
  while (lo < hi) {
    int mid = (lo + hi) >> 1;
    if (batch[mid] < g + 1) lo = mid + 1; else hi = mid;
  }
  float inv = 1.f / (float)max(lo - a, 1);

  sg[j] = pool[g * 128 + j] * inv;
  sg[j + 64] = pool[g * 128 + j + 64] * inv;
  __syncthreads();

  float acc = bc1[j];
#pragma unroll 4
  for (int k = 0; k < 128; ++k) acc += sg[k] * Wc1[k * 64 + j];  // coalesced in j
  float z = fmaxf(acc, 0.f);

  float v = z * Wc2[j];
#pragma unroll
  for (int m = 32; m > 0; m >>= 1) v += __shfl_xor(v, m, 64);
  if (j == 0) out[g] = 1.f / (1.f + expf(-(v + bc2[0])));
}

extern "C" void kernel_launch(void* const* d_in, const int* in_sizes, int n_in,
                              void* d_out, int out_size, void* d_ws, size_t ws_size,
                              hipStream_t stream) {
  const float* x   = (const float*)d_in[0];
  const int* ei    = (const int*)d_in[1];
  const int* batch = (const int*)d_in[2];
  const float* W1  = (const float*)d_in[3];
  const float* b1  = (const float*)d_in[4];
  const float* W2  = (const float*)d_in[5];
  const float* b2  = (const float*)d_in[6];
  const float* W3  = (const float*)d_in[7];
  const float* b3  = (const float*)d_in[8];
  const float* Wc1 = (const float*)d_in[9];
  const float* bc1 = (const float*)d_in[10];
  const float* Wc2 = (const float*)d_in[11];
  const float* bc2 = (const float*)d_in[12];

  int n  = in_sizes[2];
  int nE = in_sizes[1] / 2;
  const int* src = ei;
  const int* dst = ei + nE;
  int nbuk = (n + 127) >> 7;  // 128-node dst buckets

  // Workspace (~68 MB). All segment element counts multiples of 4.
  uint8_t*  tab0 = (uint8_t*)d_ws;                      // fp8 table A [n*128]
  uint8_t*  tab1 = tab0 + (size_t)n * 128;              // fp8 table B [n*128]
  float* dinv    = (float*)(tab0 + (size_t)n * 128 + (size_t)n * 256);
  int*   deg     = (int*)(dinv + n);
  int*   offs    = deg + n;                             // [n+4]
  int*   bcur    = offs + n + 4;                        // [nbuk*8*16] padded
  int*   csr     = bcur + nbuk * 8 * 16;                // [nbuk*CSRCAP]
  uint32_t* ebuf = (uint32_t*)(csr + (size_t)nbuk * CSRCAP);  // [nbuk*8*SUBCAP]
  uint16_t* WT   = (uint16_t*)(ebuf + (size_t)nbuk * 8 * SUBCAP);
  float* pool    = (float*)(WT + 3 * 16384);
  float* out     = (float*)d_out;

  hipMemsetAsync(bcur, 0, (size_t)nbuk * 8 * 16 * sizeof(int), stream);
  bucket_scatter<<<(nE + TILE - 1) / TILE, 256, 0, stream>>>(src, dst, bcur, ebuf, nE, nbuk);
  bucket_build<<<nbuk, 256, 0, stream>>>(ebuf, bcur, deg, dinv, offs, csr,
                                         W1, W2, W3, WT, pool, n, nbuk);

  int gfb = (n + 7) / 8;  // fused blocks: 8 nodes each, 1 wave/node
  gemm_mfma<true><<<(n + 63) / 64, 256, 0, stream>>>(nullptr, x, WT, dinv, tab0, n);
  gather_gemm<false><<<gfb, 512, 0, stream>>>(tab0, csr, offs, deg, dinv, b1,
                                              WT + 16384, tab1, nullptr, nullptr, n);
  gather_gemm<false><<<gfb, 512, 0, stream>>>(tab1, csr, offs, deg, dinv, b2,
                                              WT + 32768, tab0, nullptr, nullptr, n);
  gather_gemm<true><<<gfb, 512, 0, stream>>>(tab0, csr, offs, deg, dinv, b3,
                                             nullptr, nullptr, batch, pool, n);
  classifier_kernel<<<64, 64, 0, stream>>>(pool, batch, Wc1, bc1, Wc2, bc2, out, n);
}

// Round 4
// 358.547 us; speedup vs baseline: 1.2180x; 1.2180x over previous
//
#include <hip/hip_runtime.h>
#include <cstdint>
#include <cstddef>

// ---------------------------------------------------------------------------
// GCN: h = elu(D^-1/2 (A+I) D^-1/2 (h W) + b) x3, mean-pool, MLP head.
// R18: back to R16 shape (16 nodes/block, half-wave per node). R17 post-
// mortem: splitting a wave across edge halves does NOT raise per-CU in-flight
// loads (32 waves x 8 loads either way) and doubled per-node staging/MFMA ->
// regression. R18 attacks the two real costs:
//  (1) barrier tail (max-of-16 deg): nodes are assigned to blocks via a
//      (graph, deg-bin) counting-sorted permutation -> blocks see uniform
//      degree, max ~= mean. Graph-major order keeps POOL merge valid.
//  (2) latency-bound gather: load batch deepened 8 -> 16 rows in flight
//      (512 outstanding reqs/CU vs 256).
// ---------------------------------------------------------------------------

#define SUBCAP 512   // per-(bucket,XCD) capacity: mean 256, +16 sigma
#define CSRCAP 4608  // per-bucket csr region: 4096 max edges + ceil4 padding
#define TILE 4096    // edges per scatter block

typedef __attribute__((ext_vector_type(8))) short short8;   // 8 bf16 = 4 VGPRs
typedef __attribute__((ext_vector_type(4))) float f32x4;
typedef __attribute__((ext_vector_type(2))) _Float16 h16x2; // packed f16 pair

__device__ __forceinline__ float bf2f(uint32_t u) {
  return __uint_as_float(u << 16);
}
__device__ __forceinline__ uint32_t f2bf(float f) {  // round-to-nearest-even
  uint32_t x = __float_as_uint(f);
  return (x + 0x7FFFu + ((x >> 16) & 1u)) >> 16;
}

union H16 { _Float16 h; uint16_t u; };
union H2U { h16x2 h; uint32_t u; };

// f32 -> e5m2 byte (RNE via f16 then RNE-truncate mantissa to 2 bits)
__device__ __forceinline__ uint32_t f2e5m2(float f) {
  f = fminf(fmaxf(f, -30000.f), 30000.f);
  H16 cv;
  cv.h = (_Float16)f;
  uint32_t h = cv.u;
  uint32_t r = h + 0x7Fu + ((h >> 8) & 1u);
  return (r >> 8) & 0xFFu;
}

// e5m2 byte -> f32 (exact: e5m2 is truncated f16)
__device__ __forceinline__ float e5m2f(uint32_t b) {
  H16 cv;
  cv.u = (uint16_t)(b << 8);
  return (float)cv.h;
}

// ---------------- CSR build ----------------

// Block-aggregated, XCD-partitioned scatter. 4096 edges/block. (R10)
__global__ __launch_bounds__(256) void bucket_scatter(const int* __restrict__ src,
                                                      const int* __restrict__ dst,
                                                      int* __restrict__ bcur,
                                                      uint32_t* __restrict__ ebuf,
                                                      int nE, int nbuk) {
  uint32_t xcc;
  asm("s_getreg_b32 %0, hwreg(HW_REG_XCC_ID)" : "=s"(xcc));  // 0..7, wave-uniform
  __shared__ int lhist[1024];
  __shared__ int gbase[1024];
  int t = threadIdx.x;
  for (int i = t; i < nbuk; i += 256) lhist[i] = 0;
  __syncthreads();

  int e0 = blockIdx.x * TILE;
  int myd[16], mys[16], myrank[16];
#pragma unroll
  for (int j = 0; j < 16; ++j) {
    int e = e0 + t + j * 256;  // coalesced
    if (e < nE) {
      int d = dst[e];
      myd[j] = d;
      mys[j] = src[e];
      myrank[j] = atomicAdd(&lhist[d >> 7], 1);  // returns old -> local rank
    } else {
      myd[j] = -1;
    }
  }
  __syncthreads();
  for (int i = t; i < nbuk; i += 256) {
    int c = lhist[i];
    gbase[i] = c ? atomicAdd(&bcur[((i << 3) | (int)xcc) * 16], c) : 0;
  }
  __syncthreads();
#pragma unroll
  for (int j = 0; j < 16; ++j) {
    if (myd[j] >= 0) {
      int b = myd[j] >> 7;
      int pos = gbase[b] + myrank[j];
      if (pos < SUBCAP) {
        int sub = (b << 3) | (int)xcc;
        ebuf[(size_t)sub * SUBCAP + pos] =
            ((uint32_t)(myd[j] & 127) << 20) | (uint32_t)mys[j];
      }
    }
  }
}

// Fused hist + prefix + fill (R12) + side jobs: W cvt, pool zero (R14),
// (graph,deg-bin) histogram for the block-balance permutation (R18).
__global__ __launch_bounds__(256) void bucket_build(const uint32_t* __restrict__ ebuf,
                                                    const int* __restrict__ bcur,
                                                    const int* __restrict__ batch,
                                                    int* __restrict__ deg,
                                                    float* __restrict__ dinv,
                                                    int* __restrict__ offs,
                                                    int* __restrict__ csr,
                                                    const float* __restrict__ W1,
                                                    const float* __restrict__ W2,
                                                    const float* __restrict__ W3,
                                                    uint16_t* __restrict__ WT,
                                                    float* __restrict__ pool,
                                                    int* __restrict__ dhist,
                                                    int n, int nbuk) {
  int b = blockIdx.x;
  int base = b << 7;
  __shared__ int hist[128];
  __shared__ int pre[128];
  __shared__ int lcur[128];
  int t = threadIdx.x;

  // Side job 1: W1,W2,W3 fp32 [k][nn] -> WT bf16 [w][nn][k]  (grid-stride)
  for (int id = b * 256 + t; id < 3 * 16384; id += nbuk * 256) {
    int w = id >> 14;
    int rem = id & 16383;
    int k = rem >> 7, nn = rem & 127;
    const float* W = (w == 0) ? W1 : ((w == 1) ? W2 : W3);
    WT[w * 16384 + nn * 128 + k] = (uint16_t)f2bf(W[k * 128 + nn]);
  }
  // Side job 2: zero pool
  for (int id = b * 256 + t; id < 64 * 128; id += nbuk * 256) pool[id] = 0.f;

  if (t < 128) hist[t] = 0;
  __syncthreads();
  int cnts[8];
#pragma unroll
  for (int x = 0; x < 8; ++x) {
    int sub = (b << 3) | x;
    int cnt = min(bcur[sub * 16], SUBCAP);
    cnts[x] = cnt;
    const uint32_t* eb = ebuf + (size_t)sub * SUBCAP;
    for (int e = t; e < cnt; e += 256) atomicAdd(&hist[eb[e] >> 20], 1);
  }
  __syncthreads();
  if (t < 128) pre[t] = (hist[t] + 3) & ~3;  // ceil4 region sizes
  __syncthreads();
  for (int d = 1; d < 128; d <<= 1) {  // inclusive scan
    int v = (t >= d && t < 128) ? pre[t - d] : 0;
    __syncthreads();
    if (t < 128) pre[t] += v;
    __syncthreads();
  }
  if (t < 128) {
    int dg = hist[t];
    int start = b * CSRCAP + pre[t] - ((dg + 3) & ~3);  // 4-aligned
    lcur[t] = start;
    if (base + t < n) {
      deg[base + t] = dg;
      dinv[base + t] = rsqrtf((float)(dg + 1));  // +1 self-loop
      offs[base + t] = start;
      // (graph, deg-bin) histogram for perm
      atomicAdd(&dhist[batch[base + t] * 64 + min(dg, 63)], 1);
    }
  }
  __syncthreads();
#pragma unroll
  for (int x = 0; x < 8; ++x) {
    int sub = (b << 3) | x;
    int cnt = cnts[x];
    const uint32_t* eb = ebuf + (size_t)sub * SUBCAP;
    for (int e = t; e < cnt; e += 256) {
      uint32_t ed = eb[e];
      int pos = atomicAdd(&lcur[ed >> 20], 1);
      csr[pos] = (int)((ed & 0xFFFFFu) << 7);  // byte offset into fp8 table
    }
  }
}

// Exclusive prefix over the 4096 (graph,deg-bin) counters. One block.
__global__ __launch_bounds__(1024) void deg_scan(int* __restrict__ dhist) {
  __shared__ int s[1024];
  int t = threadIdx.x;
  int4 v = ((int4*)dhist)[t];
  int sum = v.x + v.y + v.z + v.w;
  s[t] = sum;
  __syncthreads();
  for (int d = 1; d < 1024; d <<= 1) {
    int w = (t >= d) ? s[t - d] : 0;
    __syncthreads();
    s[t] += w;
    __syncthreads();
  }
  int ex = s[t] - sum;  // exclusive base
  int4 o;
  o.x = ex;
  o.y = ex + v.x;
  o.z = ex + v.x + v.y;
  o.w = ex + v.x + v.y + v.z;
  ((int4*)dhist)[t] = o;
}

// Scatter node ids into perm (graph-major, deg-binned within graph).
__global__ __launch_bounds__(256) void perm_scatter(const int* __restrict__ batch,
                                                    const int* __restrict__ deg,
                                                    int* __restrict__ dhist,
                                                    int* __restrict__ perm, int n) {
  int i = blockIdx.x * 256 + threadIdx.x;
  if (i < n) {
    int k = batch[i] * 64 + min(deg[i], 63);
    perm[atomicAdd(&dhist[k], 1)] = i;
  }
}

// ---------------- MFMA GEMM (layer 1 only): fp32 in, fp8(e5m2) table out ----

template <bool F32IN>
__global__ __launch_bounds__(256) void gemm_mfma(const uint16_t* __restrict__ Xb,
                                                 const float* __restrict__ X32,
                                                 const uint16_t* __restrict__ WTb,
                                                 const float* __restrict__ dinv,
                                                 uint8_t* __restrict__ tab, int n) {
  __shared__ uint16_t sW[128 * 136];
  int t = threadIdx.x;
#pragma unroll
  for (int i = 0; i < 8; ++i) {
    int j = t + i * 256;
    int r = j >> 4, c = j & 15;
    float4 v = ((const float4*)WTb)[j];
    *(float4*)(sW + r * 136 + c * 8) = v;
  }
  __syncthreads();

  int wave = t >> 6, lane = t & 63;
  int quad = lane >> 4, l15 = lane & 15;
  int m = blockIdx.x * 64 + wave * 16 + l15;
  int mm = min(m, n - 1);

  short8 a[4];
#pragma unroll
  for (int kc = 0; kc < 4; ++kc) {
    if constexpr (F32IN) {
      const float* p = X32 + (size_t)mm * 128 + kc * 32 + quad * 8;
      float4 lo = *(const float4*)p;
      float4 hi = *(const float4*)(p + 4);
      a[kc] = (short8){(short)f2bf(lo.x), (short)f2bf(lo.y),
                       (short)f2bf(lo.z), (short)f2bf(lo.w),
                       (short)f2bf(hi.x), (short)f2bf(hi.y),
                       (short)f2bf(hi.z), (short)f2bf(hi.w)};
    } else {
      a[kc] = *(const short8*)(Xb + (size_t)mm * 128 + kc * 32 + quad * 8);
    }
  }

  f32x4 acc[8];
#pragma unroll
  for (int nn = 0; nn < 8; ++nn) acc[nn] = (f32x4){0.f, 0.f, 0.f, 0.f};

#pragma unroll
  for (int nn = 0; nn < 8; ++nn) {
    int nrow = nn * 16 + l15;
#pragma unroll
    for (int kc = 0; kc < 4; ++kc) {
      short8 b = *(const short8*)(sW + nrow * 136 + kc * 32 + quad * 8);
      acc[nn] = __builtin_amdgcn_mfma_f32_16x16x32_bf16(a[kc], b, acc[nn], 0, 0, 0);
    }
  }

  int mrow = blockIdx.x * 64 + wave * 16 + quad * 4;
#pragma unroll
  for (int r = 0; r < 4; ++r) {
    int row = mrow + r;
    if (row < n) {
      float dn = dinv[row];
#pragma unroll
      for (int nn = 0; nn < 8; ++nn) {
        tab[(size_t)row * 128 + nn * 16 + l15] = (uint8_t)f2e5m2(acc[nn][r] * dn);
      }
    }
  }
}

// ---------------- fused gather (+ next-layer GEMM | + pool) ----------------

__device__ __forceinline__ void acc_pk(uint32_t u, h16x2& a01, h16x2& a23) {
  H2U p01, p23;
  p01.u = __builtin_amdgcn_perm(u, 0u, 0x05010400u);  // (b0<<8)|(b1<<24)
  p23.u = __builtin_amdgcn_perm(u, 0u, 0x07010600u);  // (b2<<8)|(b3<<24)
  a01 += p01.h;
  a23 += p23.h;
}

// 512 threads = 16 half-waves = 16 nodes/block; node ids come from perm
// (deg-binned -> uniform trip counts -> no barrier tail). Phase 1: gather h
// rows into LDS sA (bf16), 16 rows in flight per half-wave. Phase 2 (!POOL):
// 8 waves x 4 MFMA -> tabN = fp8(dinv*(h W)). Phase 2 (POOL): threads 0..127
// merge the 16 rows (perm is graph-major => batch-sorted within block).
template <bool POOL>
__global__ __launch_bounds__(512) void gather_gemm(const uint8_t* __restrict__ tab,
                                                   const int* __restrict__ csr,
                                                   const int* __restrict__ offs,
                                                   const int* __restrict__ deg,
                                                   const float* __restrict__ dinv,
                                                   const float* __restrict__ b,
                                                   const uint16_t* __restrict__ WTb,
                                                   uint8_t* __restrict__ tabN,
                                                   const int* __restrict__ batch,
                                                   float* __restrict__ pool,
                                                   const int* __restrict__ perm,
                                                   int n) {
  __shared__ uint16_t sW[POOL ? 8 : 128 * 136];  // B operand (W^T)
  __shared__ uint16_t sA[16 * 136];              // h rows, bf16, padded stride
  __shared__ int sb[16];                         // batch ids (POOL)
  int t = threadIdx.x;
  int blk = (int)blockIdx.x;

  if constexpr (!POOL) {
#pragma unroll
    for (int i = 0; i < 4; ++i) {
      int j = t + i * 512;  // 2048 float4 = 128x128 bf16
      int r = j >> 4, c = j & 15;
      float4 v = ((const float4*)WTb)[j];
      *(float4*)(sW + r * 136 + c * 8) = v;
    }
  } else {
    if (t < 16) sb[t] = batch[perm[min(blk * 16 + t, n - 1)]];
  }

  // ---- phase 1: gather (permuted node assignment, deep load batch) ----
  int hw = t >> 5;  // 0..15 = node slot
  int node = perm[min(blk * 16 + hw, n - 1)];
  int l = t & 31;
  int c = l * 4;  // feature/byte offset within row
  const uint8_t* tabc = tab + c;
  int e0 = offs[node];  // 4-aligned by construction
  int e1 = e0 + deg[node];
  h16x2 a01 = (h16x2){(_Float16)0.f, (_Float16)0.f};
  h16x2 a23 = (h16x2){(_Float16)0.f, (_Float16)0.f};

  int e = e0;
  for (; e + 15 < e1; e += 16) {  // 16 rows in flight
    int4 c0 = *(const int4*)(csr + e);
    int4 c1 = *(const int4*)(csr + e + 4);
    int4 c2 = *(const int4*)(csr + e + 8);
    int4 c3 = *(const int4*)(csr + e + 12);
    uint32_t u[16];
    u[0]  = *(const uint32_t*)(tabc + c0.x);
    u[1]  = *(const uint32_t*)(tabc + c0.y);
    u[2]  = *(const uint32_t*)(tabc + c0.z);
    u[3]  = *(const uint32_t*)(tabc + c0.w);
    u[4]  = *(const uint32_t*)(tabc + c1.x);
    u[5]  = *(const uint32_t*)(tabc + c1.y);
    u[6]  = *(const uint32_t*)(tabc + c1.z);
    u[7]  = *(const uint32_t*)(tabc + c1.w);
    u[8]  = *(const uint32_t*)(tabc + c2.x);
    u[9]  = *(const uint32_t*)(tabc + c2.y);
    u[10] = *(const uint32_t*)(tabc + c2.z);
    u[11] = *(const uint32_t*)(tabc + c2.w);
    u[12] = *(const uint32_t*)(tabc + c3.x);
    u[13] = *(const uint32_t*)(tabc + c3.y);
    u[14] = *(const uint32_t*)(tabc + c3.z);
    u[15] = *(const uint32_t*)(tabc + c3.w);
#pragma unroll
    for (int j = 0; j < 16; ++j) acc_pk(u[j], a01, a23);
  }
  if (e + 7 < e1) {
    int4 ca = *(const int4*)(csr + e);
    int4 cb = *(const int4*)(csr + e + 4);
    uint32_t u[8];
    u[0] = *(const uint32_t*)(tabc + ca.x);
    u[1] = *(const uint32_t*)(tabc + ca.y);
    u[2] = *(const uint32_t*)(tabc + ca.z);
    u[3] = *(const uint32_t*)(tabc + ca.w);
    u[4] = *(const uint32_t*)(tabc + cb.x);
    u[5] = *(const uint32_t*)(tabc + cb.y);
    u[6] = *(const uint32_t*)(tabc + cb.z);
    u[7] = *(const uint32_t*)(tabc + cb.w);
#pragma unroll
    for (int j = 0; j < 8; ++j) acc_pk(u[j], a01, a23);
    e += 8;
  }
  if (e + 3 < e1) {
    int4 ca = *(const int4*)(csr + e);
    uint32_t u[4];
    u[0] = *(const uint32_t*)(tabc + ca.x);
    u[1] = *(const uint32_t*)(tabc + ca.y);
    u[2] = *(const uint32_t*)(tabc + ca.z);
    u[3] = *(const uint32_t*)(tabc + ca.w);
#pragma unroll
    for (int j = 0; j < 4; ++j) acc_pk(u[j], a01, a23);
    e += 4;
  }
  for (; e < e1; ++e) acc_pk(*(const uint32_t*)(tabc + csr[e]), a01, a23);

  float a0 = (float)a01.x, a1 = (float)a01.y;
  float a2 = (float)a23.x, a3 = (float)a23.y;

  float dn = dinv[node];
  uint32_t uh = *(const uint32_t*)(tabc + node * 128);  // self-loop
  float4 bb = *(const float4*)(b + c);
  float o0 = (a0 + e5m2f(uh & 0xFFu)) * dn + bb.x;
  float o1 = (a1 + e5m2f((uh >> 8) & 0xFFu)) * dn + bb.y;
  float o2 = (a2 + e5m2f((uh >> 16) & 0xFFu)) * dn + bb.z;
  float o3 = (a3 + e5m2f(uh >> 24)) * dn + bb.w;
  o0 = o0 > 0.f ? o0 : expm1f(o0);
  o1 = o1 > 0.f ? o1 : expm1f(o1);
  o2 = o2 > 0.f ? o2 : expm1f(o2);
  o3 = o3 > 0.f ? o3 : expm1f(o3);
  uint2 po;
  po.x = f2bf(o0) | (f2bf(o1) << 16);
  po.y = f2bf(o2) | (f2bf(o3) << 16);
  *(uint2*)(sA + hw * 136 + c) = po;  // h row -> LDS (bf16)
  __syncthreads();

  if constexpr (POOL) {
    // ---- phase 2: graph-major perm => sorted merge straight from LDS ----
    if (t < 128) {
      int base = blk * 16;
      int iend = min(16, n - base);
      float acc = 0.f;
      int cur = sb[0];
      for (int i = 0; i < iend; ++i) {
        int g = sb[i];
        if (g != cur) {
          atomicAdd(&pool[cur * 128 + t], acc);
          acc = 0.f;
          cur = g;
        }
        acc += bf2f((uint32_t)sA[i * 136 + t]);
      }
      atomicAdd(&pool[cur * 128 + t], acc);
    }
  } else {
    // ---- phase 2: 16x128 @ 128x128 MFMA, out -> fp8 table (perm rows) ----
    int wave = t >> 6, lane = t & 63;
    int quad = lane >> 4, l15 = lane & 15;
    f32x4 acc = (f32x4){0.f, 0.f, 0.f, 0.f};
#pragma unroll
    for (int kc = 0; kc < 4; ++kc) {
      short8 av = *(const short8*)(sA + l15 * 136 + kc * 32 + quad * 8);
      short8 bv = *(const short8*)(sW + (wave * 16 + l15) * 136 + kc * 32 + quad * 8);
      acc = __builtin_amdgcn_mfma_f32_16x16x32_bf16(av, bv, acc, 0, 0, 0);
    }
    int mrow = blk * 16 + quad * 4;
#pragma unroll
    for (int r = 0; r < 4; ++r) {
      int ri = mrow + r;
      if (ri < n) {
        int row = perm[ri];
        float dno = dinv[row];
        tabN[(size_t)row * 128 + wave * 16 + l15] = (uint8_t)f2e5m2(acc[r] * dno);
      }
    }
  }
}

// ---------------- head ----------------

// One wave per graph: cnt (binary search), z_j = relu(g.Wc1_j + bc1_j),
// logit = shfl-reduce(z_j * Wc2_j) + bc2. Coalesced Wc1 reads (lane = j).
__global__ __launch_bounds__(64) void classifier_kernel(const float* __restrict__ pool,
                                                        const int* __restrict__ batch,
                                                        const float* __restrict__ Wc1,
                                                        const float* __restrict__ bc1,
                                                        const float* __restrict__ Wc2,
                                                        const float* __restrict__ bc2,
                                                        float* __restrict__ out, int n) {
  int g = blockIdx.x;   // graph id, 0..63
  int j = threadIdx.x;  // hidden unit, 0..63
  __shared__ float sg[128];

  // cnt for this graph (all lanes redundantly; 2 binary searches)
  int lo = 0, hi = n;
  while (lo < hi) {
    int mid = (lo + hi) >> 1;
    if (batch[mid] < g) lo = mid + 1; else hi = mid;
  }
  int a = lo;
  lo = 0; hi = n;
  while (lo < hi) {
    int mid = (lo + hi) >> 1;
    if (batch[mid] < g + 1) lo = mid + 1; else hi = mid;
  }
  float inv = 1.f / (float)max(lo - a, 1);

  sg[j] = pool[g * 128 + j] * inv;
  sg[j + 64] = pool[g * 128 + j + 64] * inv;
  __syncthreads();

  float acc = bc1[j];
#pragma unroll 4
  for (int k = 0; k < 128; ++k) acc += sg[k] * Wc1[k * 64 + j];  // coalesced in j
  float z = fmaxf(acc, 0.f);

  float v = z * Wc2[j];
#pragma unroll
  for (int m = 32; m > 0; m >>= 1) v += __shfl_xor(v, m, 64);
  if (j == 0) out[g] = 1.f / (1.f + expf(-(v + bc2[0])));
}

extern "C" void kernel_launch(void* const* d_in, const int* in_sizes, int n_in,
                              void* d_out, int out_size, void* d_ws, size_t ws_size,
                              hipStream_t stream) {
  const float* x   = (const float*)d_in[0];
  const int* ei    = (const int*)d_in[1];
  const int* batch = (const int*)d_in[2];
  const float* W1  = (const float*)d_in[3];
  const float* b1  = (const float*)d_in[4];
  const float* W2  = (const float*)d_in[5];
  const float* b2  = (const float*)d_in[6];
  const float* W3  = (const float*)d_in[7];
  const float* b3  = (const float*)d_in[8];
  const float* Wc1 = (const float*)d_in[9];
  const float* bc1 = (const float*)d_in[10];
  const float* Wc2 = (const float*)d_in[11];
  const float* bc2 = (const float*)d_in[12];

  int n  = in_sizes[2];
  int nE = in_sizes[1] / 2;
  const int* src = ei;
  const int* dst = ei + nE;
  int nbuk = (n + 127) >> 7;  // 128-node dst buckets

  // Workspace (~68 MB). All segment element counts multiples of 4.
  // perm + dhist live in the n*128 slack between tab1 and dinv.
  uint8_t*  tab0 = (uint8_t*)d_ws;                      // fp8 table A [n*128]
  uint8_t*  tab1 = tab0 + (size_t)n * 128;              // fp8 table B [n*128]
  int*   perm    = (int*)(tab0 + (size_t)n * 256);      // [n]
  int*   dhist   = perm + n;                            // [4096]
  float* dinv    = (float*)(tab0 + (size_t)n * 128 + (size_t)n * 256);
  int*   deg     = (int*)(dinv + n);
  int*   offs    = deg + n;                             // [n+4]
  int*   bcur    = offs + n + 4;                        // [nbuk*8*16] padded
  int*   csr     = bcur + nbuk * 8 * 16;                // [nbuk*CSRCAP]
  uint32_t* ebuf = (uint32_t*)(csr + (size_t)nbuk * CSRCAP);  // [nbuk*8*SUBCAP]
  uint16_t* WT   = (uint16_t*)(ebuf + (size_t)nbuk * 8 * SUBCAP);
  float* pool    = (float*)(WT + 3 * 16384);
  float* out     = (float*)d_out;

  hipMemsetAsync(bcur, 0, (size_t)nbuk * 8 * 16 * sizeof(int), stream);
  hipMemsetAsync(dhist, 0, 4096 * sizeof(int), stream);
  bucket_scatter<<<(nE + TILE - 1) / TILE, 256, 0, stream>>>(src, dst, bcur, ebuf, nE, nbuk);
  bucket_build<<<nbuk, 256, 0, stream>>>(ebuf, bcur, batch, deg, dinv, offs, csr,
                                         W1, W2, W3, WT, pool, dhist, n, nbuk);
  deg_scan<<<1, 1024, 0, stream>>>(dhist);
  perm_scatter<<<(n + 255) / 256, 256, 0, stream>>>(batch, deg, dhist, perm, n);

  int gfb = (n + 15) / 16;  // fused blocks: 16 nodes each
  gemm_mfma<true><<<(n + 63) / 64, 256, 0, stream>>>(nullptr, x, WT, dinv, tab0, n);
  gather_gemm<false><<<gfb, 512, 0, stream>>>(tab0, csr, offs, deg, dinv, b1,
                                              WT + 16384, tab1, nullptr, nullptr, perm, n);
  gather_gemm<false><<<gfb, 512, 0, stream>>>(tab1, csr, offs, deg, dinv, b2,
                                              WT + 32768, tab0, nullptr, nullptr, perm, n);
  gather_gemm<true><<<gfb, 512, 0, stream>>>(tab0, csr, offs, deg, dinv, b3,
                                             nullptr, nullptr, batch, pool, perm, n);
  classifier_kernel<<<64, 64, 0, stream>>>(pool, batch, Wc1, bc1, Wc2, bc2, out, n);
}

// Round 6
// 338.787 us; speedup vs baseline: 1.2891x; 1.0583x over previous
//
#include <hip/hip_runtime.h>
#include <cstdint>
#include <cstddef>

// ---------------------------------------------------------------------------
// GCN: h = elu(D^-1/2 (A+I) D^-1/2 (h W) + b) x3, mean-pool, MLP head.
// R19: 256-thr fused gather (16 nodes, 16 lanes/node, 8 features/lane).
// R18 post-mortem: deg-binning didn't help (barrier-tail theory dead) and
// perm scattered the metadata reads (+14% FETCH). R16's POOL variant == non-
// POOL at 57us proved W-staging/MFMA aren't the cost either; the 43->57 gap
// vs barrier-free R15 is block structure. R19: halve barrier scope (4 waves),
// double blocks/CU (8), drop sW entirely (MFMA B-frags straight from L2-hot
// WT), full 16-row A-tile. Perm machinery deleted.
// (R19 resubmit -- previous round was an infra failure, not a kernel error.)
// ---------------------------------------------------------------------------

#define SUBCAP 512   // per-(bucket,XCD) capacity: mean 256, +16 sigma
#define CSRCAP 4608  // per-bucket csr region: 4096 max edges + ceil4 padding
#define TILE 4096    // edges per scatter block

typedef __attribute__((ext_vector_type(8))) short short8;   // 8 bf16 = 4 VGPRs
typedef __attribute__((ext_vector_type(4))) float f32x4;
typedef __attribute__((ext_vector_type(2))) _Float16 h16x2; // packed f16 pair

__device__ __forceinline__ float bf2f(uint32_t u) {
  return __uint_as_float(u << 16);
}
__device__ __forceinline__ uint32_t f2bf(float f) {  // round-to-nearest-even
  uint32_t x = __float_as_uint(f);
  return (x + 0x7FFFu + ((x >> 16) & 1u)) >> 16;
}

union H16 { _Float16 h; uint16_t u; };
union H2U { h16x2 h; uint32_t u; };

// f32 -> e5m2 byte (RNE via f16 then RNE-truncate mantissa to 2 bits)
__device__ __forceinline__ uint32_t f2e5m2(float f) {
  f = fminf(fmaxf(f, -30000.f), 30000.f);
  H16 cv;
  cv.h = (_Float16)f;
  uint32_t h = cv.u;
  uint32_t r = h + 0x7Fu + ((h >> 8) & 1u);
  return (r >> 8) & 0xFFu;
}

// e5m2 byte -> f32 (exact: e5m2 is truncated f16)
__device__ __forceinline__ float e5m2f(uint32_t b) {
  H16 cv;
  cv.u = (uint16_t)(b << 8);
  return (float)cv.h;
}

// ---------------- CSR build ----------------

// Block-aggregated, XCD-partitioned scatter. 4096 edges/block. (R10)
__global__ __launch_bounds__(256) void bucket_scatter(const int* __restrict__ src,
                                                      const int* __restrict__ dst,
                                                      int* __restrict__ bcur,
                                                      uint32_t* __restrict__ ebuf,
                                                      int nE, int nbuk) {
  uint32_t xcc;
  asm("s_getreg_b32 %0, hwreg(HW_REG_XCC_ID)" : "=s"(xcc));  // 0..7, wave-uniform
  __shared__ int lhist[1024];
  __shared__ int gbase[1024];
  int t = threadIdx.x;
  for (int i = t; i < nbuk; i += 256) lhist[i] = 0;
  __syncthreads();

  int e0 = blockIdx.x * TILE;
  int myd[16], mys[16], myrank[16];
#pragma unroll
  for (int j = 0; j < 16; ++j) {
    int e = e0 + t + j * 256;  // coalesced
    if (e < nE) {
      int d = dst[e];
      myd[j] = d;
      mys[j] = src[e];
      myrank[j] = atomicAdd(&lhist[d >> 7], 1);  // returns old -> local rank
    } else {
      myd[j] = -1;
    }
  }
  __syncthreads();
  for (int i = t; i < nbuk; i += 256) {
    int c = lhist[i];
    gbase[i] = c ? atomicAdd(&bcur[((i << 3) | (int)xcc) * 16], c) : 0;
  }
  __syncthreads();
#pragma unroll
  for (int j = 0; j < 16; ++j) {
    if (myd[j] >= 0) {
      int b = myd[j] >> 7;
      int pos = gbase[b] + myrank[j];
      if (pos < SUBCAP) {
        int sub = (b << 3) | (int)xcc;
        ebuf[(size_t)sub * SUBCAP + pos] =
            ((uint32_t)(myd[j] & 127) << 20) | (uint32_t)mys[j];
      }
    }
  }
}

// Fused hist + prefix + fill (R12) + side jobs: W cvt, pool zero (R14).
__global__ __launch_bounds__(256) void bucket_build(const uint32_t* __restrict__ ebuf,
                                                    const int* __restrict__ bcur,
                                                    int* __restrict__ deg,
                                                    float* __restrict__ dinv,
                                                    int* __restrict__ offs,
                                                    int* __restrict__ csr,
                                                    const float* __restrict__ W1,
                                                    const float* __restrict__ W2,
                                                    const float* __restrict__ W3,
                                                    uint16_t* __restrict__ WT,
                                                    float* __restrict__ pool,
                                                    int n, int nbuk) {
  int b = blockIdx.x;
  int base = b << 7;
  __shared__ int hist[128];
  __shared__ int pre[128];
  __shared__ int lcur[128];
  int t = threadIdx.x;

  // Side job 1: W1,W2,W3 fp32 [k][nn] -> WT bf16 [w][nn][k]  (grid-stride)
  for (int id = b * 256 + t; id < 3 * 16384; id += nbuk * 256) {
    int w = id >> 14;
    int rem = id & 16383;
    int k = rem >> 7, nn = rem & 127;
    const float* W = (w == 0) ? W1 : ((w == 1) ? W2 : W3);
    WT[w * 16384 + nn * 128 + k] = (uint16_t)f2bf(W[k * 128 + nn]);
  }
  // Side job 2: zero pool
  for (int id = b * 256 + t; id < 64 * 128; id += nbuk * 256) pool[id] = 0.f;

  if (t < 128) hist[t] = 0;
  __syncthreads();
  int cnts[8];
#pragma unroll
  for (int x = 0; x < 8; ++x) {
    int sub = (b << 3) | x;
    int cnt = min(bcur[sub * 16], SUBCAP);
    cnts[x] = cnt;
    const uint32_t* eb = ebuf + (size_t)sub * SUBCAP;
    for (int e = t; e < cnt; e += 256) atomicAdd(&hist[eb[e] >> 20], 1);
  }
  __syncthreads();
  if (t < 128) pre[t] = (hist[t] + 3) & ~3;  // ceil4 region sizes
  __syncthreads();
  for (int d = 1; d < 128; d <<= 1) {  // inclusive scan
    int v = (t >= d && t < 128) ? pre[t - d] : 0;
    __syncthreads();
    if (t < 128) pre[t] += v;
    __syncthreads();
  }
  if (t < 128) {
    int dg = hist[t];
    int start = b * CSRCAP + pre[t] - ((dg + 3) & ~3);  // 4-aligned
    lcur[t] = start;
    if (base + t < n) {
      deg[base + t] = dg;
      dinv[base + t] = rsqrtf((float)(dg + 1));  // +1 self-loop
      offs[base + t] = start;
    }
  }
  __syncthreads();
#pragma unroll
  for (int x = 0; x < 8; ++x) {
    int sub = (b << 3) | x;
    int cnt = cnts[x];
    const uint32_t* eb = ebuf + (size_t)sub * SUBCAP;
    for (int e = t; e < cnt; e += 256) {
      uint32_t ed = eb[e];
      int pos = atomicAdd(&lcur[ed >> 20], 1);
      csr[pos] = (int)((ed & 0xFFFFFu) << 7);  // byte offset into fp8 table
    }
  }
}

// ---------------- MFMA GEMM (layer 1 only): fp32 in, fp8(e5m2) table out ----

template <bool F32IN>
__global__ __launch_bounds__(256) void gemm_mfma(const uint16_t* __restrict__ Xb,
                                                 const float* __restrict__ X32,
                                                 const uint16_t* __restrict__ WTb,
                                                 const float* __restrict__ dinv,
                                                 uint8_t* __restrict__ tab, int n) {
  __shared__ uint16_t sW[128 * 136];
  int t = threadIdx.x;
#pragma unroll
  for (int i = 0; i < 8; ++i) {
    int j = t + i * 256;
    int r = j >> 4, c = j & 15;
    float4 v = ((const float4*)WTb)[j];
    *(float4*)(sW + r * 136 + c * 8) = v;
  }
  __syncthreads();

  int wave = t >> 6, lane = t & 63;
  int quad = lane >> 4, l15 = lane & 15;
  int m = blockIdx.x * 64 + wave * 16 + l15;
  int mm = min(m, n - 1);

  short8 a[4];
#pragma unroll
  for (int kc = 0; kc < 4; ++kc) {
    if constexpr (F32IN) {
      const float* p = X32 + (size_t)mm * 128 + kc * 32 + quad * 8;
      float4 lo = *(const float4*)p;
      float4 hi = *(const float4*)(p + 4);
      a[kc] = (short8){(short)f2bf(lo.x), (short)f2bf(lo.y),
                       (short)f2bf(lo.z), (short)f2bf(lo.w),
                       (short)f2bf(hi.x), (short)f2bf(hi.y),
                       (short)f2bf(hi.z), (short)f2bf(hi.w)};
    } else {
      a[kc] = *(const short8*)(Xb + (size_t)mm * 128 + kc * 32 + quad * 8);
    }
  }

  f32x4 acc[8];
#pragma unroll
  for (int nn = 0; nn < 8; ++nn) acc[nn] = (f32x4){0.f, 0.f, 0.f, 0.f};

#pragma unroll
  for (int nn = 0; nn < 8; ++nn) {
    int nrow = nn * 16 + l15;
#pragma unroll
    for (int kc = 0; kc < 4; ++kc) {
      short8 b = *(const short8*)(sW + nrow * 136 + kc * 32 + quad * 8);
      acc[nn] = __builtin_amdgcn_mfma_f32_16x16x32_bf16(a[kc], b, acc[nn], 0, 0, 0);
    }
  }

  int mrow = blockIdx.x * 64 + wave * 16 + quad * 4;
#pragma unroll
  for (int r = 0; r < 4; ++r) {
    int row = mrow + r;
    if (row < n) {
      float dn = dinv[row];
#pragma unroll
      for (int nn = 0; nn < 8; ++nn) {
        tab[(size_t)row * 128 + nn * 16 + l15] = (uint8_t)f2e5m2(acc[nn][r] * dn);
      }
    }
  }
}

// ---------------- fused gather (+ next-layer GEMM | + pool) ----------------

// accumulate 8 e5m2 bytes (one uint2) into 4 packed-f16 pairs
__device__ __forceinline__ void acc_pk8(uint2 u, h16x2& a01, h16x2& a23,
                                        h16x2& a45, h16x2& a67) {
  H2U p01, p23, p45, p67;
  p01.u = __builtin_amdgcn_perm(u.x, 0u, 0x05010400u);  // (b0<<8)|(b1<<24)
  p23.u = __builtin_amdgcn_perm(u.x, 0u, 0x07010600u);  // (b2<<8)|(b3<<24)
  p45.u = __builtin_amdgcn_perm(u.y, 0u, 0x05010400u);
  p67.u = __builtin_amdgcn_perm(u.y, 0u, 0x07010600u);
  a01 += p01.h;
  a23 += p23.h;
  a45 += p45.h;
  a67 += p67.h;
}

// 256 threads = 16 groups of 16 lanes = 16 nodes/block (4 waves).
// Phase 1: each 16-lane group gathers its node's row (8 features/lane,
// uint2 row loads, 8 rows in flight) -> elu -> bf16 row into LDS sA.
// Phase 2 (!POOL): 4 waves x 8 MFMA (full 16-row A-tile, B-frags straight
// from L2-hot global WT -- no sW staging) -> tabN = fp8(dinv*(h W)).
// Phase 2 (POOL): threads 0..127 mean-pool the 16 rows straight from LDS.
template <bool POOL>
__global__ __launch_bounds__(256) void gather_gemm(const uint8_t* __restrict__ tab,
                                                   const int* __restrict__ csr,
                                                   const int* __restrict__ offs,
                                                   const int* __restrict__ deg,
                                                   const float* __restrict__ dinv,
                                                   const float* __restrict__ b,
                                                   const uint16_t* __restrict__ WTb,
                                                   uint8_t* __restrict__ tabN,
                                                   const int* __restrict__ batch,
                                                   float* __restrict__ pool,
                                                   int n) {
  __shared__ uint16_t sA[16 * 136];  // h rows, bf16, padded stride
  __shared__ int sb[16];             // batch ids (POOL)
  int t = threadIdx.x;
  int blk = (int)blockIdx.x;

  if constexpr (POOL) {
    if (t < 16) sb[t] = batch[min(blk * 16 + t, n - 1)];
  }

  // ---- phase 1: gather (16 lanes per node, 8 features per lane) ----
  int grp = t >> 4;  // 0..15 = node slot
  int l = t & 15;
  int node = min(blk * 16 + grp, n - 1);
  int c = l * 8;  // feature/byte offset within row
  const uint8_t* tabc = tab + c;
  int e0 = offs[node];  // 4-aligned by construction
  int e1 = e0 + deg[node];
  h16x2 a01 = (h16x2){(_Float16)0.f, (_Float16)0.f};
  h16x2 a23 = a01, a45 = a01, a67 = a01;

  int e = e0;
  for (; e + 7 < e1; e += 8) {  // 8 rows in flight
    int4 c0 = *(const int4*)(csr + e);
    int4 c1 = *(const int4*)(csr + e + 4);
    uint2 u[8];
    u[0] = *(const uint2*)(tabc + c0.x);
    u[1] = *(const uint2*)(tabc + c0.y);
    u[2] = *(const uint2*)(tabc + c0.z);
    u[3] = *(const uint2*)(tabc + c0.w);
    u[4] = *(const uint2*)(tabc + c1.x);
    u[5] = *(const uint2*)(tabc + c1.y);
    u[6] = *(const uint2*)(tabc + c1.z);
    u[7] = *(const uint2*)(tabc + c1.w);
#pragma unroll
    for (int j = 0; j < 8; ++j) acc_pk8(u[j], a01, a23, a45, a67);
  }
  if (e + 3 < e1) {
    int4 c0 = *(const int4*)(csr + e);
    uint2 u[4];
    u[0] = *(const uint2*)(tabc + c0.x);
    u[1] = *(const uint2*)(tabc + c0.y);
    u[2] = *(const uint2*)(tabc + c0.z);
    u[3] = *(const uint2*)(tabc + c0.w);
#pragma unroll
    for (int j = 0; j < 4; ++j) acc_pk8(u[j], a01, a23, a45, a67);
    e += 4;
  }
  for (; e < e1; ++e)
    acc_pk8(*(const uint2*)(tabc + csr[e]), a01, a23, a45, a67);

  float f0 = (float)a01.x, f1 = (float)a01.y;
  float f2 = (float)a23.x, f3 = (float)a23.y;
  float f4 = (float)a45.x, f5 = (float)a45.y;
  float f6 = (float)a67.x, f7 = (float)a67.y;

  float dn = dinv[node];
  uint2 uh = *(const uint2*)(tabc + node * 128);  // self-loop (8 bytes)
  float4 bb0 = *(const float4*)(b + c);
  float4 bb1 = *(const float4*)(b + c + 4);
  float o0 = (f0 + e5m2f(uh.x & 0xFFu)) * dn + bb0.x;
  float o1 = (f1 + e5m2f((uh.x >> 8) & 0xFFu)) * dn + bb0.y;
  float o2 = (f2 + e5m2f((uh.x >> 16) & 0xFFu)) * dn + bb0.z;
  float o3 = (f3 + e5m2f(uh.x >> 24)) * dn + bb0.w;
  float o4 = (f4 + e5m2f(uh.y & 0xFFu)) * dn + bb1.x;
  float o5 = (f5 + e5m2f((uh.y >> 8) & 0xFFu)) * dn + bb1.y;
  float o6 = (f6 + e5m2f((uh.y >> 16) & 0xFFu)) * dn + bb1.z;
  float o7 = (f7 + e5m2f(uh.y >> 24)) * dn + bb1.w;
  o0 = o0 > 0.f ? o0 : expm1f(o0);
  o1 = o1 > 0.f ? o1 : expm1f(o1);
  o2 = o2 > 0.f ? o2 : expm1f(o2);
  o3 = o3 > 0.f ? o3 : expm1f(o3);
  o4 = o4 > 0.f ? o4 : expm1f(o4);
  o5 = o5 > 0.f ? o5 : expm1f(o5);
  o6 = o6 > 0.f ? o6 : expm1f(o6);
  o7 = o7 > 0.f ? o7 : expm1f(o7);
  uint4 po;
  po.x = f2bf(o0) | (f2bf(o1) << 16);
  po.y = f2bf(o2) | (f2bf(o3) << 16);
  po.z = f2bf(o4) | (f2bf(o5) << 16);
  po.w = f2bf(o6) | (f2bf(o7) << 16);
  *(uint4*)(sA + grp * 136 + c) = po;  // h row -> LDS (bf16)
  __syncthreads();

  if constexpr (POOL) {
    // ---- phase 2: sorted-batch mean-pool straight from LDS ----
    if (t < 128) {
      int base = blk * 16;
      int iend = min(16, n - base);
      float acc = 0.f;
      int cur = sb[0];
      for (int i = 0; i < iend; ++i) {
        int g = sb[i];
        if (g != cur) {
          atomicAdd(&pool[cur * 128 + t], acc);
          acc = 0.f;
          cur = g;
        }
        acc += bf2f((uint32_t)sA[i * 136 + t]);
      }
      atomicAdd(&pool[cur * 128 + t], acc);
    }
  } else {
    // ---- phase 2: 16x128 @ 128x128 MFMA, B-frags from global WT ----
    int wave = t >> 6, lane = t & 63;
    int quad = lane >> 4, l15 = lane & 15;
    short8 av[4];
#pragma unroll
    for (int kc = 0; kc < 4; ++kc)
      av[kc] = *(const short8*)(sA + l15 * 136 + kc * 32 + quad * 8);
    f32x4 acc0 = (f32x4){0.f, 0.f, 0.f, 0.f};
    f32x4 acc1 = (f32x4){0.f, 0.f, 0.f, 0.f};
#pragma unroll
    for (int kc = 0; kc < 4; ++kc) {
      short8 bv0 = *(const short8*)(WTb + (wave * 32 + l15) * 128 + kc * 32 + quad * 8);
      acc0 = __builtin_amdgcn_mfma_f32_16x16x32_bf16(av[kc], bv0, acc0, 0, 0, 0);
      short8 bv1 = *(const short8*)(WTb + (wave * 32 + 16 + l15) * 128 + kc * 32 + quad * 8);
      acc1 = __builtin_amdgcn_mfma_f32_16x16x32_bf16(av[kc], bv1, acc1, 0, 0, 0);
    }
    int mrow = blk * 16 + quad * 4;
#pragma unroll
    for (int r = 0; r < 4; ++r) {
      int row = mrow + r;
      if (row < n) {
        float dno = dinv[row];
        tabN[(size_t)row * 128 + wave * 32 + l15] = (uint8_t)f2e5m2(acc0[r] * dno);
        tabN[(size_t)row * 128 + wave * 32 + 16 + l15] = (uint8_t)f2e5m2(acc1[r] * dno);
      }
    }
  }
}

// ---------------- head ----------------

// One wave per graph: cnt (binary search), z_j = relu(g.Wc1_j + bc1_j),
// logit = shfl-reduce(z_j * Wc2_j) + bc2. Coalesced Wc1 reads (lane = j).
__global__ __launch_bounds__(64) void classifier_kernel(const float* __restrict__ pool,
                                                        const int* __restrict__ batch,
                                                        const float* __restrict__ Wc1,
                                                        const float* __restrict__ bc1,
                                                        const float* __restrict__ Wc2,
                                                        const float* __restrict__ bc2,
                                                        float* __restrict__ out, int n) {
  int g = blockIdx.x;   // graph id, 0..63
  int j = threadIdx.x;  // hidden unit, 0..63
  __shared__ float sg[128];

  // cnt for this graph (all lanes redundantly; 2 binary searches)
  int lo = 0, hi = n;
  while (lo < hi) {
    int mid = (lo + hi) >> 1;
    if (batch[mid] < g) lo = mid + 1; else hi = mid;
  }
  int a = lo;
  lo = 0; hi = n;
  while (lo < hi) {
    int mid = (lo + hi) >> 1;
    if (batch[mid] < g + 1) lo = mid + 1; else hi = mid;
  }
  float inv = 1.f / (float)max(lo - a, 1);

  sg[j] = pool[g * 128 + j] * inv;
  sg[j + 64] = pool[g * 128 + j + 64] * inv;
  __syncthreads();

  float acc = bc1[j];
#pragma unroll 4
  for (int k = 0; k < 128; ++k) acc += sg[k] * Wc1[k * 64 + j];  // coalesced in j
  float z = fmaxf(acc, 0.f);

  float v = z * Wc2[j];
#pragma unroll
  for (int m = 32; m > 0; m >>= 1) v += __shfl_xor(v, m, 64);
  if (j == 0) out[g] = 1.f / (1.f + expf(-(v + bc2[0])));
}

extern "C" void kernel_launch(void* const* d_in, const int* in_sizes, int n_in,
                              void* d_out, int out_size, void* d_ws, size_t ws_size,
                              hipStream_t stream) {
  const float* x   = (const float*)d_in[0];
  const int* ei    = (const int*)d_in[1];
  const int* batch = (const int*)d_in[2];
  const float* W1  = (const float*)d_in[3];
  const float* b1  = (const float*)d_in[4];
  const float* W2  = (const float*)d_in[5];
  const float* b2  = (const float*)d_in[6];
  const float* W3  = (const float*)d_in[7];
  const float* b3  = (const float*)d_in[8];
  const float* Wc1 = (const float*)d_in[9];
  const float* bc1 = (const float*)d_in[10];
  const float* Wc2 = (const float*)d_in[11];
  const float* bc2 = (const float*)d_in[12];

  int n  = in_sizes[2];
  int nE = in_sizes[1] / 2;
  const int* src = ei;
  const int* dst = ei + nE;
  int nbuk = (n + 127) >> 7;  // 128-node dst buckets

  // Workspace (~68 MB). All segment element counts multiples of 4.
  uint8_t*  tab0 = (uint8_t*)d_ws;                      // fp8 table A [n*128]
  uint8_t*  tab1 = tab0 + (size_t)n * 128;              // fp8 table B [n*128]
  float* dinv    = (float*)(tab0 + (size_t)n * 128 + (size_t)n * 256);
  int*   deg     = (int*)(dinv + n);
  int*   offs    = deg + n;                             // [n+4]
  int*   bcur    = offs + n + 4;                        // [nbuk*8*16] padded
  int*   csr     = bcur + nbuk * 8 * 16;                // [nbuk*CSRCAP]
  uint32_t* ebuf = (uint32_t*)(csr + (size_t)nbuk * CSRCAP);  // [nbuk*8*SUBCAP]
  uint16_t* WT   = (uint16_t*)(ebuf + (size_t)nbuk * 8 * SUBCAP);
  float* pool    = (float*)(WT + 3 * 16384);
  float* out     = (float*)d_out;

  hipMemsetAsync(bcur, 0, (size_t)nbuk * 8 * 16 * sizeof(int), stream);
  bucket_scatter<<<(nE + TILE - 1) / TILE, 256, 0, stream>>>(src, dst, bcur, ebuf, nE, nbuk);
  bucket_build<<<nbuk, 256, 0, stream>>>(ebuf, bcur, deg, dinv, offs, csr,
                                         W1, W2, W3, WT, pool, n, nbuk);

  int gfb = (n + 15) / 16;  // fused blocks: 16 nodes each
  gemm_mfma<true><<<(n + 63) / 64, 256, 0, stream>>>(nullptr, x, WT, dinv, tab0, n);
  gather_gemm<false><<<gfb, 256, 0, stream>>>(tab0, csr, offs, deg, dinv, b1,
                                              WT + 16384, tab1, nullptr, nullptr, n);
  gather_gemm<false><<<gfb, 256, 0, stream>>>(tab1, csr, offs, deg, dinv, b2,
                                              WT + 32768, tab0, nullptr, nullptr, n);
  gather_gemm<true><<<gfb, 256, 0, stream>>>(tab0, csr, offs, deg, dinv, b3,
                                             nullptr, nullptr, batch, pool, n);
  classifier_kernel<<<64, 64, 0, stream>>>(pool, batch, Wc1, bc1, Wc2, bc2, out, n);
}

// Round 7
// 320.302 us; speedup vs baseline: 1.3635x; 1.0577x over previous
//
#include <hip/hip_runtime.h>
#include <cstdint>
#include <cstddef>

// ---------------------------------------------------------------------------
// GCN: h = elu(D^-1/2 (A+I) D^-1/2 (h W) + b) x3, mean-pool, MLP head.
// R20: back to the R16 fused structure exactly (best measured: 57.2us), plus
// zero-row csr padding. Structure matrix: 32-lane/no-barrier=43.3 (R15),
// 32-lane/8-wave-barrier=57.2 (R16), 16-lane/4-wave=64.5 (R19). R19's B-from-
// global + 16-lane groups didn't cut VALU work (26us both) and widened
// divergence -> reverted. New: each fp8 table gets a zero row at index n;
// bucket_build fills csr pad slots [deg, ceil4(deg)) with its offset, so the
// gather runs pure 8/4 batches over ceil4(deg) -- no scalar tail, uniform
// mod-4 trip counts. f16 + 0.0 is exact -> bit-stable; pad fetches hit one
// L1-resident line.
// ---------------------------------------------------------------------------

#define SUBCAP 512   // per-(bucket,XCD) capacity: mean 256, +16 sigma
#define CSRCAP 4608  // per-bucket csr region: 4096 max edges + ceil4 padding
#define TILE 4096    // edges per scatter block

typedef __attribute__((ext_vector_type(8))) short short8;   // 8 bf16 = 4 VGPRs
typedef __attribute__((ext_vector_type(4))) float f32x4;
typedef __attribute__((ext_vector_type(2))) _Float16 h16x2; // packed f16 pair

__device__ __forceinline__ float bf2f(uint32_t u) {
  return __uint_as_float(u << 16);
}
__device__ __forceinline__ uint32_t f2bf(float f) {  // round-to-nearest-even
  uint32_t x = __float_as_uint(f);
  return (x + 0x7FFFu + ((x >> 16) & 1u)) >> 16;
}

union H16 { _Float16 h; uint16_t u; };
union H2U { h16x2 h; uint32_t u; };

// f32 -> e5m2 byte (RNE via f16 then RNE-truncate mantissa to 2 bits)
__device__ __forceinline__ uint32_t f2e5m2(float f) {
  f = fminf(fmaxf(f, -30000.f), 30000.f);
  H16 cv;
  cv.h = (_Float16)f;
  uint32_t h = cv.u;
  uint32_t r = h + 0x7Fu + ((h >> 8) & 1u);
  return (r >> 8) & 0xFFu;
}

// e5m2 byte -> f32 (exact: e5m2 is truncated f16)
__device__ __forceinline__ float e5m2f(uint32_t b) {
  H16 cv;
  cv.u = (uint16_t)(b << 8);
  return (float)cv.h;
}

// ---------------- CSR build ----------------

// Block-aggregated, XCD-partitioned scatter. 4096 edges/block. (R10)
__global__ __launch_bounds__(256) void bucket_scatter(const int* __restrict__ src,
                                                      const int* __restrict__ dst,
                                                      int* __restrict__ bcur,
                                                      uint32_t* __restrict__ ebuf,
                                                      int nE, int nbuk) {
  uint32_t xcc;
  asm("s_getreg_b32 %0, hwreg(HW_REG_XCC_ID)" : "=s"(xcc));  // 0..7, wave-uniform
  __shared__ int lhist[1024];
  __shared__ int gbase[1024];
  int t = threadIdx.x;
  for (int i = t; i < nbuk; i += 256) lhist[i] = 0;
  __syncthreads();

  int e0 = blockIdx.x * TILE;
  int myd[16], mys[16], myrank[16];
#pragma unroll
  for (int j = 0; j < 16; ++j) {
    int e = e0 + t + j * 256;  // coalesced
    if (e < nE) {
      int d = dst[e];
      myd[j] = d;
      mys[j] = src[e];
      myrank[j] = atomicAdd(&lhist[d >> 7], 1);  // returns old -> local rank
    } else {
      myd[j] = -1;
    }
  }
  __syncthreads();
  for (int i = t; i < nbuk; i += 256) {
    int c = lhist[i];
    gbase[i] = c ? atomicAdd(&bcur[((i << 3) | (int)xcc) * 16], c) : 0;
  }
  __syncthreads();
#pragma unroll
  for (int j = 0; j < 16; ++j) {
    if (myd[j] >= 0) {
      int b = myd[j] >> 7;
      int pos = gbase[b] + myrank[j];
      if (pos < SUBCAP) {
        int sub = (b << 3) | (int)xcc;
        ebuf[(size_t)sub * SUBCAP + pos] =
            ((uint32_t)(myd[j] & 127) << 20) | (uint32_t)mys[j];
      }
    }
  }
}

// Fused hist + prefix + fill (R12) + side jobs: W cvt, pool zero, zero-row
// zero (R20). Epilogue fills csr pad slots with the zero-row offset.
__global__ __launch_bounds__(256) void bucket_build(const uint32_t* __restrict__ ebuf,
                                                    const int* __restrict__ bcur,
                                                    int* __restrict__ deg,
                                                    float* __restrict__ dinv,
                                                    int* __restrict__ offs,
                                                    int* __restrict__ csr,
                                                    const float* __restrict__ W1,
                                                    const float* __restrict__ W2,
                                                    const float* __restrict__ W3,
                                                    uint16_t* __restrict__ WT,
                                                    float* __restrict__ pool,
                                                    uint32_t* __restrict__ z0,
                                                    uint32_t* __restrict__ z1,
                                                    int n, int nbuk) {
  int b = blockIdx.x;
  int base = b << 7;
  __shared__ int hist[128];
  __shared__ int pre[128];
  __shared__ int lcur[128];
  int t = threadIdx.x;

  // Side job 1: W1,W2,W3 fp32 [k][nn] -> WT bf16 [w][nn][k]  (grid-stride)
  for (int id = b * 256 + t; id < 3 * 16384; id += nbuk * 256) {
    int w = id >> 14;
    int rem = id & 16383;
    int k = rem >> 7, nn = rem & 127;
    const float* W = (w == 0) ? W1 : ((w == 1) ? W2 : W3);
    WT[w * 16384 + nn * 128 + k] = (uint16_t)f2bf(W[k * 128 + nn]);
  }
  // Side job 2: zero pool
  for (int id = b * 256 + t; id < 64 * 128; id += nbuk * 256) pool[id] = 0.f;
  // Side job 3: zero the zero rows of both fp8 tables (32 u32 each)
  for (int id = b * 256 + t; id < 32; id += nbuk * 256) {
    z0[id] = 0u;
    z1[id] = 0u;
  }

  if (t < 128) hist[t] = 0;
  __syncthreads();
  int cnts[8];
#pragma unroll
  for (int x = 0; x < 8; ++x) {
    int sub = (b << 3) | x;
    int cnt = min(bcur[sub * 16], SUBCAP);
    cnts[x] = cnt;
    const uint32_t* eb = ebuf + (size_t)sub * SUBCAP;
    for (int e = t; e < cnt; e += 256) atomicAdd(&hist[eb[e] >> 20], 1);
  }
  __syncthreads();
  if (t < 128) pre[t] = (hist[t] + 3) & ~3;  // ceil4 region sizes
  __syncthreads();
  for (int d = 1; d < 128; d <<= 1) {  // inclusive scan
    int v = (t >= d && t < 128) ? pre[t - d] : 0;
    __syncthreads();
    if (t < 128) pre[t] += v;
    __syncthreads();
  }
  if (t < 128) {
    int dg = hist[t];
    int start = b * CSRCAP + pre[t] - ((dg + 3) & ~3);  // 4-aligned
    lcur[t] = start;
    if (base + t < n) {
      deg[base + t] = dg;
      dinv[base + t] = rsqrtf((float)(dg + 1));  // +1 self-loop
      offs[base + t] = start;
    }
  }
  __syncthreads();
#pragma unroll
  for (int x = 0; x < 8; ++x) {
    int sub = (b << 3) | x;
    int cnt = cnts[x];
    const uint32_t* eb = ebuf + (size_t)sub * SUBCAP;
    for (int e = t; e < cnt; e += 256) {
      uint32_t ed = eb[e];
      int pos = atomicAdd(&lcur[ed >> 20], 1);
      csr[pos] = (int)((ed & 0xFFFFFu) << 7);  // byte offset into fp8 table
    }
  }
  __syncthreads();
  // Pad slots [deg, ceil4(deg)) -> zero-row offset (row n): gather runs
  // pure 4-aligned batches with no scalar tail.
  if (t < 128) {
    int dg = hist[t];
    int c4 = (dg + 3) & ~3;
    int start = b * CSRCAP + pre[t] - c4;
    int zoff = n << 7;
    for (int p = dg; p < c4; ++p) csr[start + p] = zoff;
  }
}

// ---------------- MFMA GEMM (layer 1 only): fp32 in, fp8(e5m2) table out ----

template <bool F32IN>
__global__ __launch_bounds__(256) void gemm_mfma(const uint16_t* __restrict__ Xb,
                                                 const float* __restrict__ X32,
                                                 const uint16_t* __restrict__ WTb,
                                                 const float* __restrict__ dinv,
                                                 uint8_t* __restrict__ tab, int n) {
  __shared__ uint16_t sW[128 * 136];
  int t = threadIdx.x;
#pragma unroll
  for (int i = 0; i < 8; ++i) {
    int j = t + i * 256;
    int r = j >> 4, c = j & 15;
    float4 v = ((const float4*)WTb)[j];
    *(float4*)(sW + r * 136 + c * 8) = v;
  }
  __syncthreads();

  int wave = t >> 6, lane = t & 63;
  int quad = lane >> 4, l15 = lane & 15;
  int m = blockIdx.x * 64 + wave * 16 + l15;
  int mm = min(m, n - 1);

  short8 a[4];
#pragma unroll
  for (int kc = 0; kc < 4; ++kc) {
    if constexpr (F32IN) {
      const float* p = X32 + (size_t)mm * 128 + kc * 32 + quad * 8;
      float4 lo = *(const float4*)p;
      float4 hi = *(const float4*)(p + 4);
      a[kc] = (short8){(short)f2bf(lo.x), (short)f2bf(lo.y),
                       (short)f2bf(lo.z), (short)f2bf(lo.w),
                       (short)f2bf(hi.x), (short)f2bf(hi.y),
                       (short)f2bf(hi.z), (short)f2bf(hi.w)};
    } else {
      a[kc] = *(const short8*)(Xb + (size_t)mm * 128 + kc * 32 + quad * 8);
    }
  }

  f32x4 acc[8];
#pragma unroll
  for (int nn = 0; nn < 8; ++nn) acc[nn] = (f32x4){0.f, 0.f, 0.f, 0.f};

#pragma unroll
  for (int nn = 0; nn < 8; ++nn) {
    int nrow = nn * 16 + l15;
#pragma unroll
    for (int kc = 0; kc < 4; ++kc) {
      short8 b = *(const short8*)(sW + nrow * 136 + kc * 32 + quad * 8);
      acc[nn] = __builtin_amdgcn_mfma_f32_16x16x32_bf16(a[kc], b, acc[nn], 0, 0, 0);
    }
  }

  int mrow = blockIdx.x * 64 + wave * 16 + quad * 4;
#pragma unroll
  for (int r = 0; r < 4; ++r) {
    int row = mrow + r;
    if (row < n) {
      float dn = dinv[row];
#pragma unroll
      for (int nn = 0; nn < 8; ++nn) {
        tab[(size_t)row * 128 + nn * 16 + l15] = (uint8_t)f2e5m2(acc[nn][r] * dn);
      }
    }
  }
}

// ---------------- fused gather (+ next-layer GEMM | + pool) ----------------

__device__ __forceinline__ void acc_pk(uint32_t u, h16x2& a01, h16x2& a23) {
  H2U p01, p23;
  p01.u = __builtin_amdgcn_perm(u, 0u, 0x05010400u);  // (b0<<8)|(b1<<24)
  p23.u = __builtin_amdgcn_perm(u, 0u, 0x07010600u);  // (b2<<8)|(b3<<24)
  a01 += p01.h;
  a23 += p23.h;
}

// 512 threads = 16 half-waves = 16 nodes/block. Phase 1: gather h rows into
// LDS sA (bf16); edge lists are ceil4-padded with zero-row entries -> pure
// 8/4 batches, no scalar tail. Phase 2 (!POOL): 8 waves x 4 MFMA -> tabN =
// fp8(dinv*(h W)). Phase 2 (POOL): threads 0..127 mean-pool from LDS.
template <bool POOL>
__global__ __launch_bounds__(512) void gather_gemm(const uint8_t* __restrict__ tab,
                                                   const int* __restrict__ csr,
                                                   const int* __restrict__ offs,
                                                   const int* __restrict__ deg,
                                                   const float* __restrict__ dinv,
                                                   const float* __restrict__ b,
                                                   const uint16_t* __restrict__ WTb,
                                                   uint8_t* __restrict__ tabN,
                                                   const int* __restrict__ batch,
                                                   float* __restrict__ pool,
                                                   int n) {
  __shared__ uint16_t sW[POOL ? 8 : 128 * 136];  // B operand (W^T)
  __shared__ uint16_t sA[16 * 136];              // h rows, bf16, padded stride
  __shared__ int sb[16];                         // batch ids (POOL)
  int t = threadIdx.x;
  int blk = (int)blockIdx.x;

  if constexpr (!POOL) {
#pragma unroll
    for (int i = 0; i < 4; ++i) {
      int j = t + i * 512;  // 2048 float4 = 128x128 bf16
      int r = j >> 4, c = j & 15;
      float4 v = ((const float4*)WTb)[j];
      *(float4*)(sW + r * 136 + c * 8) = v;
    }
  } else {
    if (t < 16) sb[t] = batch[min(blk * 16 + t, n - 1)];
  }

  // ---- phase 1: gather (half-wave per node, tail-free 4-aligned loop) ----
  int hw = t >> 5;  // 0..15 = node slot
  int node = min(blk * 16 + hw, n - 1);
  int l = t & 31;
  int c = l * 4;  // feature/byte offset within row
  const uint8_t* tabc = tab + c;
  int e0 = offs[node];                     // 4-aligned by construction
  int e1 = e0 + ((deg[node] + 3) & ~3);    // ceil4: pads hit the zero row
  h16x2 a01 = (h16x2){(_Float16)0.f, (_Float16)0.f};
  h16x2 a23 = (h16x2){(_Float16)0.f, (_Float16)0.f};

  int e = e0;
  for (; e + 7 < e1; e += 8) {
    int4 ca = *(const int4*)(csr + e);
    int4 cb = *(const int4*)(csr + e + 4);
    uint32_t u[8];
    u[0] = *(const uint32_t*)(tabc + ca.x);
    u[1] = *(const uint32_t*)(tabc + ca.y);
    u[2] = *(const uint32_t*)(tabc + ca.z);
    u[3] = *(const uint32_t*)(tabc + ca.w);
    u[4] = *(const uint32_t*)(tabc + cb.x);
    u[5] = *(const uint32_t*)(tabc + cb.y);
    u[6] = *(const uint32_t*)(tabc + cb.z);
    u[7] = *(const uint32_t*)(tabc + cb.w);
#pragma unroll
    for (int j = 0; j < 8; ++j) acc_pk(u[j], a01, a23);
  }
  if (e < e1) {  // exactly one 4-batch possible (ceil4 % 8 ∈ {0,4})
    int4 ca = *(const int4*)(csr + e);
    uint32_t u[4];
    u[0] = *(const uint32_t*)(tabc + ca.x);
    u[1] = *(const uint32_t*)(tabc + ca.y);
    u[2] = *(const uint32_t*)(tabc + ca.z);
    u[3] = *(const uint32_t*)(tabc + ca.w);
#pragma unroll
    for (int j = 0; j < 4; ++j) acc_pk(u[j], a01, a23);
  }

  float a0 = (float)a01.x, a1 = (float)a01.y;
  float a2 = (float)a23.x, a3 = (float)a23.y;

  float dn = dinv[node];
  uint32_t uh = *(const uint32_t*)(tabc + node * 128);  // self-loop
  float4 bb = *(const float4*)(b + c);
  float o0 = (a0 + e5m2f(uh & 0xFFu)) * dn + bb.x;
  float o1 = (a1 + e5m2f((uh >> 8) & 0xFFu)) * dn + bb.y;
  float o2 = (a2 + e5m2f((uh >> 16) & 0xFFu)) * dn + bb.z;
  float o3 = (a3 + e5m2f(uh >> 24)) * dn + bb.w;
  o0 = o0 > 0.f ? o0 : expm1f(o0);
  o1 = o1 > 0.f ? o1 : expm1f(o1);
  o2 = o2 > 0.f ? o2 : expm1f(o2);
  o3 = o3 > 0.f ? o3 : expm1f(o3);
  uint2 po;
  po.x = f2bf(o0) | (f2bf(o1) << 16);
  po.y = f2bf(o2) | (f2bf(o3) << 16);
  *(uint2*)(sA + hw * 136 + c) = po;  // h row -> LDS (bf16)
  __syncthreads();

  if constexpr (POOL) {
    // ---- phase 2: sorted-batch mean-pool straight from LDS ----
    if (t < 128) {
      int base = blk * 16;
      int iend = min(16, n - base);
      float acc = 0.f;
      int cur = sb[0];
      for (int i = 0; i < iend; ++i) {
        int g = sb[i];
        if (g != cur) {
          atomicAdd(&pool[cur * 128 + t], acc);
          acc = 0.f;
          cur = g;
        }
        acc += bf2f((uint32_t)sA[i * 136 + t]);
      }
      atomicAdd(&pool[cur * 128 + t], acc);
    }
  } else {
    // ---- phase 2: 16x128 @ 128x128 MFMA, out -> fp8 table ----
    int wave = t >> 6, lane = t & 63;
    int quad = lane >> 4, l15 = lane & 15;
    f32x4 acc = (f32x4){0.f, 0.f, 0.f, 0.f};
#pragma unroll
    for (int kc = 0; kc < 4; ++kc) {
      short8 av = *(const short8*)(sA + l15 * 136 + kc * 32 + quad * 8);
      short8 bv = *(const short8*)(sW + (wave * 16 + l15) * 136 + kc * 32 + quad * 8);
      acc = __builtin_amdgcn_mfma_f32_16x16x32_bf16(av, bv, acc, 0, 0, 0);
    }
    int mrow = blk * 16 + quad * 4;
#pragma unroll
    for (int r = 0; r < 4; ++r) {
      int row = mrow + r;
      if (row < n) {
        float dno = dinv[row];
        tabN[(size_t)row * 128 + wave * 16 + l15] = (uint8_t)f2e5m2(acc[r] * dno);
      }
    }
  }
}

// ---------------- head ----------------

// One wave per graph: cnt (binary search), z_j = relu(g.Wc1_j + bc1_j),
// logit = shfl-reduce(z_j * Wc2_j) + bc2. Coalesced Wc1 reads (lane = j).
__global__ __launch_bounds__(64) void classifier_kernel(const float* __restrict__ pool,
                                                        const int* __restrict__ batch,
                                                        const float* __restrict__ Wc1,
                                                        const float* __restrict__ bc1,
                                                        const float* __restrict__ Wc2,
                                                        const float* __restrict__ bc2,
                                                        float* __restrict__ out, int n) {
  int g = blockIdx.x;   // graph id, 0..63
  int j = threadIdx.x;  // hidden unit, 0..63
  __shared__ float sg[128];

  // cnt for this graph (all lanes redundantly; 2 binary searches)
  int lo = 0, hi = n;
  while (lo < hi) {
    int mid = (lo + hi) >> 1;
    if (batch[mid] < g) lo = mid + 1; else hi = mid;
  }
  int a = lo;
  lo = 0; hi = n;
  while (lo < hi) {
    int mid = (lo + hi) >> 1;
    if (batch[mid] < g + 1) lo = mid + 1; else hi = mid;
  }
  float inv = 1.f / (float)max(lo - a, 1);

  sg[j] = pool[g * 128 + j] * inv;
  sg[j + 64] = pool[g * 128 + j + 64] * inv;
  __syncthreads();

  float acc = bc1[j];
#pragma unroll 4
  for (int k = 0; k < 128; ++k) acc += sg[k] * Wc1[k * 64 + j];  // coalesced in j
  float z = fmaxf(acc, 0.f);

  float v = z * Wc2[j];
#pragma unroll
  for (int m = 32; m > 0; m >>= 1) v += __shfl_xor(v, m, 64);
  if (j == 0) out[g] = 1.f / (1.f + expf(-(v + bc2[0])));
}

extern "C" void kernel_launch(void* const* d_in, const int* in_sizes, int n_in,
                              void* d_out, int out_size, void* d_ws, size_t ws_size,
                              hipStream_t stream) {
  const float* x   = (const float*)d_in[0];
  const int* ei    = (const int*)d_in[1];
  const int* batch = (const int*)d_in[2];
  const float* W1  = (const float*)d_in[3];
  const float* b1  = (const float*)d_in[4];
  const float* W2  = (const float*)d_in[5];
  const float* b2  = (const float*)d_in[6];
  const float* W3  = (const float*)d_in[7];
  const float* b3  = (const float*)d_in[8];
  const float* Wc1 = (const float*)d_in[9];
  const float* bc1 = (const float*)d_in[10];
  const float* Wc2 = (const float*)d_in[11];
  const float* bc2 = (const float*)d_in[12];

  int n  = in_sizes[2];
  int nE = in_sizes[1] / 2;
  const int* src = ei;
  const int* dst = ei + nE;
  int nbuk = (n + 127) >> 7;  // 128-node dst buckets

  // Workspace (~68 MB). Tables are (n+4) rows: row n is the shared zero row
  // used by csr pad entries. All segment element counts multiples of 4.
  size_t T = (size_t)(n + 4) * 128;  // table stride in bytes
  uint8_t*  tab0 = (uint8_t*)d_ws;                      // fp8 table A
  uint8_t*  tab1 = tab0 + T;                            // fp8 table B
  float* dinv    = (float*)(tab1 + T);
  int*   deg     = (int*)(dinv + n);
  int*   offs    = deg + n;                             // [n+4]
  int*   bcur    = offs + n + 4;                        // [nbuk*8*16] padded
  int*   csr     = bcur + nbuk * 8 * 16;                // [nbuk*CSRCAP]
  uint32_t* ebuf = (uint32_t*)(csr + (size_t)nbuk * CSRCAP);  // [nbuk*8*SUBCAP]
  uint16_t* WT   = (uint16_t*)(ebuf + (size_t)nbuk * 8 * SUBCAP);
  float* pool    = (float*)(WT + 3 * 16384);
  float* out     = (float*)d_out;

  hipMemsetAsync(bcur, 0, (size_t)nbuk * 8 * 16 * sizeof(int), stream);
  bucket_scatter<<<(nE + TILE - 1) / TILE, 256, 0, stream>>>(src, dst, bcur, ebuf, nE, nbuk);
  bucket_build<<<nbuk, 256, 0, stream>>>(ebuf, bcur, deg, dinv, offs, csr,
                                         W1, W2, W3, WT, pool,
                                         (uint32_t*)(tab0 + (size_t)n * 128),
                                         (uint32_t*)(tab1 + (size_t)n * 128),
                                         n, nbuk);

  int gfb = (n + 15) / 16;  // fused blocks: 16 nodes each
  gemm_mfma<true><<<(n + 63) / 64, 256, 0, stream>>>(nullptr, x, WT, dinv, tab0, n);
  gather_gemm<false><<<gfb, 512, 0, stream>>>(tab0, csr, offs, deg, dinv, b1,
                                              WT + 16384, tab1, nullptr, nullptr, n);
  gather_gemm<false><<<gfb, 512, 0, stream>>>(tab1, csr, offs, deg, dinv, b2,
                                              WT + 32768, tab0, nullptr, nullptr, n);
  gather_gemm<true><<<gfb, 512, 0, stream>>>(tab0, csr, offs, deg, dinv, b3,
                                             nullptr, nullptr, batch, pool, n);
  classifier_kernel<<<64, 64, 0, stream>>>(pool, batch, Wc1, bc1, Wc2, bc2, out, n);
}